// Round 1
// baseline (3313.708 us; speedup 1.0000x reference)
//
#include <hip/hip_runtime.h>

// Problem constants
#define HDIM 1024
#define IDIM 2816
#define NEXP 8
#define NTOK 4096      // B*S = 2*2048
#define NROWS 8192     // NTOK * K(=2)
#define RPAD 8320      // NROWS + 128 pad rows (tile overrun)

typedef short bf16x8 __attribute__((ext_vector_type(8)));
typedef float f32x4 __attribute__((ext_vector_type(4)));

__device__ __forceinline__ float bf2f(unsigned int u) {
    union { unsigned int i; float f; } v; v.i = u << 16; return v.f;
}
__device__ __forceinline__ unsigned short f2bf(float f) {
    union { float f; unsigned int i; } v; v.f = f;
    unsigned int r = (v.i + 0x7fffu + ((v.i >> 16) & 1u)) >> 16;  // RNE
    return (unsigned short)r;
}

// ---------------------------------------------------------------------------
// 1) Gating: one wave per token. fp64 accumulate for stable top-2 ordering.
//    Writes logits (fp32) to d_out tail, topi/topv, atomic expert counts.
// ---------------------------------------------------------------------------
__global__ __launch_bounds__(256) void gating_kernel(
    const float* __restrict__ x, const float* __restrict__ Wgate,
    const float* __restrict__ bgate, float* __restrict__ logits_out,
    int* __restrict__ counts, int* __restrict__ topi, float* __restrict__ topv)
{
    int wave = (blockIdx.x << 2) + (threadIdx.x >> 6);
    int lane = threadIdx.x & 63;
    if (wave >= NTOK) return;
    const float* xr = x + (size_t)wave * HDIM;

    double acc[NEXP];
#pragma unroll
    for (int e = 0; e < NEXP; ++e) acc[e] = 0.0;

    for (int it = 0; it < HDIM / 64; ++it) {
        int h = lane + (it << 6);
        float xv = xr[h];
        const float* wr = Wgate + (size_t)h * NEXP;
#pragma unroll
        for (int e = 0; e < NEXP; ++e) acc[e] += (double)xv * (double)wr[e];
    }
#pragma unroll
    for (int e = 0; e < NEXP; ++e) {
        double v = acc[e];
        for (int off = 32; off; off >>= 1) v += __shfl_xor(v, off, 64);
        acc[e] = v + (double)bgate[e];
    }
    float lf[NEXP];
#pragma unroll
    for (int e = 0; e < NEXP; ++e) lf[e] = (float)acc[e];

    if (lane < NEXP) logits_out[(size_t)wave * NEXP + lane] = lf[lane];

    if (lane == 0) {
        int i1 = 0; float v1 = lf[0];
#pragma unroll
        for (int e = 1; e < NEXP; ++e) if (lf[e] > v1) { v1 = lf[e]; i1 = e; }
        int i2 = -1; float v2 = -3.0e38f;
#pragma unroll
        for (int e = 0; e < NEXP; ++e) {
            if (e == i1) continue;
            if (lf[e] > v2) { v2 = lf[e]; i2 = e; }
        }
        topi[wave * 2 + 0] = i1; topv[wave * 2 + 0] = v1;
        topi[wave * 2 + 1] = i2; topv[wave * 2 + 1] = v2;
        atomicAdd(&counts[i1], 1);
        atomicAdd(&counts[i2], 1);
    }
}

// ---------------------------------------------------------------------------
// 2) Offsets: tiny prefix sum, sets cursors.
// ---------------------------------------------------------------------------
__global__ void offsets_kernel(const int* __restrict__ counts,
                               int* __restrict__ offs, int* __restrict__ cursor)
{
    if (threadIdx.x == 0 && blockIdx.x == 0) {
        int s = 0;
        for (int e = 0; e < NEXP; ++e) { offs[e] = s; cursor[e] = s; s += counts[e]; }
        offs[NEXP] = s;
    }
}

// ---------------------------------------------------------------------------
// 3) Scatter/gather: one wave per (token, k) pair. Packs x row as bf16 into
//    X_gath[pos], records pos_of and per-row combine weight.
// ---------------------------------------------------------------------------
__global__ __launch_bounds__(256) void scatter_kernel(
    const float* __restrict__ x, const int* __restrict__ topi,
    const float* __restrict__ topv, int* __restrict__ cursor,
    float* __restrict__ row_w, int* __restrict__ pos_of,
    unsigned short* __restrict__ Xg)
{
    int p = (blockIdx.x << 2) + (threadIdx.x >> 6);
    int lane = threadIdx.x & 63;
    if (p >= NROWS) return;
    int n = p >> 1;
    int e = topi[p];
    float w = topv[p];
    int pos = 0;
    if (lane == 0) {
        pos = atomicAdd(&cursor[e], 1);
        row_w[pos] = w;
        pos_of[p] = pos;
    }
    pos = __shfl(pos, 0, 64);
    const float* xr = x + (size_t)n * HDIM;
    unsigned short* dst = Xg + (size_t)pos * HDIM;
#pragma unroll
    for (int it = 0; it < HDIM / 256; ++it) {
        int idx = (it * 64 + lane) * 4;
        float4 v = *reinterpret_cast<const float4*>(&xr[idx]);
        ushort4 o;
        o.x = f2bf(v.x); o.y = f2bf(v.y); o.z = f2bf(v.z); o.w = f2bf(v.w);
        *reinterpret_cast<ushort4*>(&dst[idx]) = o;
    }
}

// ---------------------------------------------------------------------------
// 4) Fused gate+up GEMM: per-expert row groups. 128x128 tile, BK=32,
//    4 waves each computing a 64x64 quadrant (4x4 frags of 16x16x32 bf16).
//    B operand (fp32 weights) converted in-register and transposed into LDS.
//    Epilogue: h = silu(g)*u -> bf16.
// ---------------------------------------------------------------------------
#define LDP 40  // padded LDS row stride (bf16 elems): 80B, 16B-aligned, ~2-way banks

__global__ __launch_bounds__(256) void gateup_kernel(
    const unsigned short* __restrict__ Xg,
    const float* __restrict__ Wg, const float* __restrict__ Wu,
    const int* __restrict__ offs, unsigned short* __restrict__ hbuf)
{
    __shared__ unsigned short As[128 * LDP];
    __shared__ unsigned short Bg[128 * LDP];
    __shared__ unsigned short Bu[128 * LDP];

    const int e = blockIdx.x >> 5;
    const int mt = blockIdx.x & 31;
    const int r0 = offs[e], r1 = offs[e + 1];
    const int m0 = r0 + mt * 128;
    if (m0 >= r1) return;
    const int n0 = blockIdx.y * 128;

    const float* wg = Wg + (size_t)e * HDIM * IDIM;
    const float* wu = Wu + (size_t)e * HDIM * IDIM;

    const int tid = threadIdx.x;
    const int lane = tid & 63;
    const int wv = tid >> 6;
    const int wr = (wv >> 1) * 64;
    const int wc = (wv & 1) * 64;
    const int lr = lane & 15;
    const int kg = (lane >> 4) * 8;

    f32x4 zero = {0.f, 0.f, 0.f, 0.f};
    f32x4 accg[4][4], accu[4][4];
#pragma unroll
    for (int m = 0; m < 4; ++m)
#pragma unroll
        for (int n = 0; n < 4; ++n) { accg[m][n] = zero; accu[m][n] = zero; }

    for (int k0 = 0; k0 < HDIM; k0 += 32) {
        __syncthreads();
        // Stage A (bf16, already packed): 128 rows x 32 k
#pragma unroll
        for (int it = 0; it < 2; ++it) {
            int chunk = it * 256 + tid;
            int row = chunk >> 2, c = (chunk & 3) * 8;
            uint4 v = *reinterpret_cast<const uint4*>(&Xg[(size_t)(m0 + row) * HDIM + k0 + c]);
            *reinterpret_cast<uint4*>(&As[row * LDP + c]) = v;
        }
        // Stage B (fp32 -> bf16, transposed to [i][k])
#pragma unroll
        for (int it = 0; it < 4; ++it) {
            int chunk = it * 256 + tid;
            int row = chunk >> 5;          // h 0..31
            int c4 = (chunk & 31) * 4;     // i
            float4 vg = *reinterpret_cast<const float4*>(&wg[(size_t)(k0 + row) * IDIM + n0 + c4]);
            float4 vu = *reinterpret_cast<const float4*>(&wu[(size_t)(k0 + row) * IDIM + n0 + c4]);
            Bg[(c4 + 0) * LDP + row] = f2bf(vg.x);
            Bg[(c4 + 1) * LDP + row] = f2bf(vg.y);
            Bg[(c4 + 2) * LDP + row] = f2bf(vg.z);
            Bg[(c4 + 3) * LDP + row] = f2bf(vg.w);
            Bu[(c4 + 0) * LDP + row] = f2bf(vu.x);
            Bu[(c4 + 1) * LDP + row] = f2bf(vu.y);
            Bu[(c4 + 2) * LDP + row] = f2bf(vu.z);
            Bu[(c4 + 3) * LDP + row] = f2bf(vu.w);
        }
        __syncthreads();

        bf16x8 af[4], bgf[4], buf[4];
#pragma unroll
        for (int m = 0; m < 4; ++m)
            af[m] = *reinterpret_cast<const bf16x8*>(&As[(wr + m * 16 + lr) * LDP + kg]);
#pragma unroll
        for (int n = 0; n < 4; ++n) {
            bgf[n] = *reinterpret_cast<const bf16x8*>(&Bg[(wc + n * 16 + lr) * LDP + kg]);
            buf[n] = *reinterpret_cast<const bf16x8*>(&Bu[(wc + n * 16 + lr) * LDP + kg]);
        }
#pragma unroll
        for (int m = 0; m < 4; ++m)
#pragma unroll
            for (int n = 0; n < 4; ++n) {
                accg[m][n] = __builtin_amdgcn_mfma_f32_16x16x32_bf16(af[m], bgf[n], accg[m][n], 0, 0, 0);
                accu[m][n] = __builtin_amdgcn_mfma_f32_16x16x32_bf16(af[m], buf[n], accu[m][n], 0, 0, 0);
            }
    }

    const int rr = (lane >> 4) * 4;
#pragma unroll
    for (int m = 0; m < 4; ++m) {
#pragma unroll
        for (int r = 0; r < 4; ++r) {
            int grow = m0 + wr + m * 16 + rr + r;
            if (grow < r1) {
                unsigned short* hr = &hbuf[(size_t)grow * IDIM + n0 + wc + lr];
#pragma unroll
                for (int n = 0; n < 4; ++n) {
                    float g = accg[m][n][r];
                    float u = accu[m][n][r];
                    float s = g / (1.0f + __expf(-g));
                    hr[n * 16] = f2bf(s * u);
                }
            }
        }
    }
}

// ---------------------------------------------------------------------------
// 5) Down GEMM: [rows, I] @ Wd[e] (I x H), scaled by per-row combine weight,
//    writes bf16 eo rows.
// ---------------------------------------------------------------------------
__global__ __launch_bounds__(256) void down_kernel(
    const unsigned short* __restrict__ hbuf,
    const float* __restrict__ Wd,
    const int* __restrict__ offs,
    const float* __restrict__ row_w,
    unsigned short* __restrict__ eo)
{
    __shared__ unsigned short As[128 * LDP];
    __shared__ unsigned short Bs[128 * LDP];

    const int e = blockIdx.x >> 5;
    const int mt = blockIdx.x & 31;
    const int r0 = offs[e], r1 = offs[e + 1];
    const int m0 = r0 + mt * 128;
    if (m0 >= r1) return;
    const int n0 = blockIdx.y * 128;   // over HDIM

    const float* wd = Wd + (size_t)e * IDIM * HDIM;

    const int tid = threadIdx.x;
    const int lane = tid & 63;
    const int wv = tid >> 6;
    const int wr = (wv >> 1) * 64;
    const int wc = (wv & 1) * 64;
    const int lr = lane & 15;
    const int kg = (lane >> 4) * 8;

    f32x4 zero = {0.f, 0.f, 0.f, 0.f};
    f32x4 acc[4][4];
#pragma unroll
    for (int m = 0; m < 4; ++m)
#pragma unroll
        for (int n = 0; n < 4; ++n) acc[m][n] = zero;

    for (int k0 = 0; k0 < IDIM; k0 += 32) {
        __syncthreads();
#pragma unroll
        for (int it = 0; it < 2; ++it) {
            int chunk = it * 256 + tid;
            int row = chunk >> 2, c = (chunk & 3) * 8;
            uint4 v = *reinterpret_cast<const uint4*>(&hbuf[(size_t)(m0 + row) * IDIM + k0 + c]);
            *reinterpret_cast<uint4*>(&As[row * LDP + c]) = v;
        }
#pragma unroll
        for (int it = 0; it < 4; ++it) {
            int chunk = it * 256 + tid;
            int row = chunk >> 5;          // i 0..31
            int c4 = (chunk & 31) * 4;     // h
            float4 vd = *reinterpret_cast<const float4*>(&wd[(size_t)(k0 + row) * HDIM + n0 + c4]);
            Bs[(c4 + 0) * LDP + row] = f2bf(vd.x);
            Bs[(c4 + 1) * LDP + row] = f2bf(vd.y);
            Bs[(c4 + 2) * LDP + row] = f2bf(vd.z);
            Bs[(c4 + 3) * LDP + row] = f2bf(vd.w);
        }
        __syncthreads();

        bf16x8 af[4], bf[4];
#pragma unroll
        for (int m = 0; m < 4; ++m)
            af[m] = *reinterpret_cast<const bf16x8*>(&As[(wr + m * 16 + lr) * LDP + kg]);
#pragma unroll
        for (int n = 0; n < 4; ++n)
            bf[n] = *reinterpret_cast<const bf16x8*>(&Bs[(wc + n * 16 + lr) * LDP + kg]);
#pragma unroll
        for (int m = 0; m < 4; ++m)
#pragma unroll
            for (int n = 0; n < 4; ++n)
                acc[m][n] = __builtin_amdgcn_mfma_f32_16x16x32_bf16(af[m], bf[n], acc[m][n], 0, 0, 0);
    }

    const int rr = (lane >> 4) * 4;
#pragma unroll
    for (int m = 0; m < 4; ++m) {
#pragma unroll
        for (int r = 0; r < 4; ++r) {
            int grow = m0 + wr + m * 16 + rr + r;
            if (grow < r1) {
                float w = row_w[grow];
                unsigned short* er = &eo[(size_t)grow * HDIM + n0 + wc + lr];
#pragma unroll
                for (int n = 0; n < 4; ++n)
                    er[n * 16] = f2bf(acc[m][n][r] * w);
            }
        }
    }
}

// ---------------------------------------------------------------------------
// 6) Combine: out[n] = eo[pos0] + eo[pos1]  (weights already applied)
// ---------------------------------------------------------------------------
__global__ __launch_bounds__(256) void combine_kernel(
    const unsigned short* __restrict__ eo, const int* __restrict__ pos_of,
    float* __restrict__ out)
{
    int t = blockIdx.x * 256 + threadIdx.x;       // 0 .. NTOK*HDIM/8 - 1
    int n = t >> 7;                               // HDIM/8 = 128 chunks/token
    int c = (t & 127) << 3;
    int p0 = pos_of[n * 2 + 0];
    int p1 = pos_of[n * 2 + 1];
    uint4 a = *reinterpret_cast<const uint4*>(&eo[(size_t)p0 * HDIM + c]);
    uint4 b = *reinterpret_cast<const uint4*>(&eo[(size_t)p1 * HDIM + c]);
    float4 o0, o1;
    o0.x = bf2f(a.x & 0xffffu) + bf2f(b.x & 0xffffu);
    o0.y = bf2f(a.x >> 16)     + bf2f(b.x >> 16);
    o0.z = bf2f(a.y & 0xffffu) + bf2f(b.y & 0xffffu);
    o0.w = bf2f(a.y >> 16)     + bf2f(b.y >> 16);
    o1.x = bf2f(a.z & 0xffffu) + bf2f(b.z & 0xffffu);
    o1.y = bf2f(a.z >> 16)     + bf2f(b.z >> 16);
    o1.z = bf2f(a.w & 0xffffu) + bf2f(b.w & 0xffffu);
    o1.w = bf2f(a.w >> 16)     + bf2f(b.w >> 16);
    float* op = out + (size_t)n * HDIM + c;
    *reinterpret_cast<float4*>(op) = o0;
    *reinterpret_cast<float4*>(op + 4) = o1;
}

// ---------------------------------------------------------------------------
// ws layout (bytes):
//   [0,            17,039,360)  X_gath bf16 [RPAD][HDIM]   (later aliased by eo)
//   [17,039,360,   63,897,600)  hbuf   bf16 [RPAD][IDIM]
//   [63,897,600,   ...       )  meta: counts(32) offs(@64) cursor(@128)
//                               topi(@256) topv(@33024) pos_of(@65792) row_w(@98560)
// total ~64.03 MB
// ---------------------------------------------------------------------------
extern "C" void kernel_launch(void* const* d_in, const int* in_sizes, int n_in,
                              void* d_out, int out_size, void* d_ws, size_t ws_size,
                              hipStream_t stream)
{
    const float* x     = (const float*)d_in[0];
    const float* Wgate = (const float*)d_in[1];
    const float* bgate = (const float*)d_in[2];
    const float* Wg    = (const float*)d_in[3];
    const float* Wu    = (const float*)d_in[4];
    const float* Wd    = (const float*)d_in[5];
    float* out = (float*)d_out;
    float* logits = out + (size_t)NTOK * HDIM;

    char* ws = (char*)d_ws;
    unsigned short* Xg   = (unsigned short*)ws;            // also eo
    unsigned short* hbuf = (unsigned short*)(ws + 17039360);
    char* meta = ws + 63897600;
    int*   counts = (int*)(meta);
    int*   offs   = (int*)(meta + 64);
    int*   cursor = (int*)(meta + 128);
    int*   topi   = (int*)(meta + 256);
    float* topv   = (float*)(meta + 33024);
    int*   pos_of = (int*)(meta + 65792);
    float* row_w  = (float*)(meta + 98560);

    hipMemsetAsync(counts, 0, 32, stream);
    gating_kernel<<<NTOK / 4, 256, 0, stream>>>(x, Wgate, bgate, logits, counts, topi, topv);
    offsets_kernel<<<1, 64, 0, stream>>>(counts, offs, cursor);
    scatter_kernel<<<NROWS / 4, 256, 0, stream>>>(x, topi, topv, cursor, row_w, pos_of, Xg);
    dim3 gC(NEXP * 32, IDIM / 128);
    gateup_kernel<<<gC, 256, 0, stream>>>(Xg, Wg, Wu, offs, hbuf);
    dim3 gD(NEXP * 32, HDIM / 128);
    down_kernel<<<gD, 256, 0, stream>>>(hbuf, Wd, offs, row_w, Xg /*eo*/);
    combine_kernel<<<NTOK * HDIM / 8 / 256, 256, 0, stream>>>(Xg, pos_of, out);
}

// Round 2
// 560.750 us; speedup vs baseline: 5.9094x; 5.9094x over previous
//
#include <hip/hip_runtime.h>

// Problem constants
#define HDIM 1024
#define IDIM 2816
#define NEXP 8
#define NTOK 4096      // B*S
#define NROWS 8192     // NTOK * K(=2)
#define RPAD 8320      // NROWS + 128 pad rows (tile overrun)
#define MT   64        // max 128-row tiles per expert (worst-case skew)
#define GU_NY 22       // IDIM/128
#define DN_NY 8        // HDIM/128

typedef short bf16x8 __attribute__((ext_vector_type(8)));
typedef float f32x4 __attribute__((ext_vector_type(4)));
typedef unsigned short u16x8 __attribute__((ext_vector_type(8)));

static __device__ __forceinline__ float bf2f(unsigned int u) {
    union { unsigned int i; float f; } v; v.i = u << 16; return v.f;
}
static __device__ __forceinline__ unsigned short f2bf(float f) {
    union { float f; unsigned int i; } v; v.f = f;
    return (unsigned short)((v.i + 0x7fffu + ((v.i >> 16) & 1u)) >> 16);  // RNE
}

// async global->LDS, 16B per lane. LDS dest must be linear in lane order.
static __device__ __forceinline__ void gload16(const void* g, void* l) {
    __builtin_amdgcn_global_load_lds(
        (const __attribute__((address_space(1))) unsigned int*)g,
        (__attribute__((address_space(3))) unsigned int*)l, 16, 0, 0);
}

// ---------------------------------------------------------------------------
// 1) Gating: one wave per token, fp64 accumulate for stable top-2 ordering.
// ---------------------------------------------------------------------------
__global__ __launch_bounds__(256) void gating_kernel(
    const float* __restrict__ x, const float* __restrict__ Wgate,
    const float* __restrict__ bgate, float* __restrict__ logits_out,
    int* __restrict__ counts, int* __restrict__ topi, float* __restrict__ topv)
{
    int wave = (blockIdx.x << 2) + (threadIdx.x >> 6);
    int lane = threadIdx.x & 63;
    if (wave >= NTOK) return;
    const float* xr = x + (size_t)wave * HDIM;

    double acc[NEXP];
#pragma unroll
    for (int e = 0; e < NEXP; ++e) acc[e] = 0.0;

    for (int it = 0; it < HDIM / 64; ++it) {
        int h = lane + (it << 6);
        float xv = xr[h];
        const float* wr = Wgate + (size_t)h * NEXP;
#pragma unroll
        for (int e = 0; e < NEXP; ++e) acc[e] += (double)xv * (double)wr[e];
    }
#pragma unroll
    for (int e = 0; e < NEXP; ++e) {
        double v = acc[e];
        for (int off = 32; off; off >>= 1) v += __shfl_xor(v, off, 64);
        acc[e] = v + (double)bgate[e];
    }
    float lf[NEXP];
#pragma unroll
    for (int e = 0; e < NEXP; ++e) lf[e] = (float)acc[e];

    if (lane < NEXP) logits_out[(size_t)wave * NEXP + lane] = lf[lane];

    if (lane == 0) {
        int i1 = 0; float v1 = lf[0];
#pragma unroll
        for (int e = 1; e < NEXP; ++e) if (lf[e] > v1) { v1 = lf[e]; i1 = e; }
        int i2 = -1; float v2 = -3.0e38f;
#pragma unroll
        for (int e = 0; e < NEXP; ++e) {
            if (e == i1) continue;
            if (lf[e] > v2) { v2 = lf[e]; i2 = e; }
        }
        topi[wave * 2 + 0] = i1; topv[wave * 2 + 0] = v1;
        topi[wave * 2 + 1] = i2; topv[wave * 2 + 1] = v2;
        atomicAdd(&counts[i1], 1);
        atomicAdd(&counts[i2], 1);
    }
}

// ---------------------------------------------------------------------------
// 2) Offsets
// ---------------------------------------------------------------------------
__global__ void offsets_kernel(const int* __restrict__ counts,
                               int* __restrict__ offs, int* __restrict__ cursor)
{
    if (threadIdx.x == 0 && blockIdx.x == 0) {
        int s = 0;
        for (int e = 0; e < NEXP; ++e) { offs[e] = s; cursor[e] = s; s += counts[e]; }
        offs[NEXP] = s;
    }
}

// ---------------------------------------------------------------------------
// 3) Scatter: pack selected token rows as bf16 into Xg[pos]
// ---------------------------------------------------------------------------
__global__ __launch_bounds__(256) void scatter_kernel(
    const float* __restrict__ x, const int* __restrict__ topi,
    const float* __restrict__ topv, int* __restrict__ cursor,
    float* __restrict__ row_w, int* __restrict__ pos_of,
    unsigned short* __restrict__ Xg)
{
    int p = (blockIdx.x << 2) + (threadIdx.x >> 6);
    int lane = threadIdx.x & 63;
    if (p >= NROWS) return;
    int n = p >> 1;
    int e = topi[p];
    float w = topv[p];
    int pos = 0;
    if (lane == 0) {
        pos = atomicAdd(&cursor[e], 1);
        row_w[pos] = w;
        pos_of[p] = pos;
    }
    pos = __shfl(pos, 0, 64);
    const float* xr = x + (size_t)n * HDIM;
    unsigned short* dst = Xg + (size_t)pos * HDIM;
#pragma unroll
    for (int it = 0; it < HDIM / 256; ++it) {
        int idx = (it * 64 + lane) * 4;
        float4 v = *reinterpret_cast<const float4*>(&xr[idx]);
        ushort4 o;
        o.x = f2bf(v.x); o.y = f2bf(v.y); o.z = f2bf(v.z); o.w = f2bf(v.w);
        *reinterpret_cast<ushort4*>(&dst[idx]) = o;
    }
}

// ---------------------------------------------------------------------------
// 4) Weight convert+transpose: fp32 src[R][C] -> bf16 dst[C][R], per expert.
//    64x64 tiles via LDS (pad 66: phase-1 writes 2-way, phase-2 reads 4-way).
// ---------------------------------------------------------------------------
__global__ __launch_bounds__(256) void transpose_cvt_kernel(
    const float* __restrict__ src, unsigned short* __restrict__ dst,
    int R, int C, int TC)
{
    __shared__ unsigned short lds[64 * 66];
    int e = blockIdx.y;
    const float* s0 = src + (size_t)e * R * C;
    unsigned short* d0 = dst + (size_t)e * R * C;
    int tt = blockIdx.x;
    int tr = tt / TC, tc = tt % TC;
    int tid = threadIdx.x;
    {
        int r = tid >> 2, c0 = (tid & 3) << 4;
        const float* s = s0 + (size_t)(tr * 64 + r) * C + tc * 64 + c0;
        float4 v0 = *reinterpret_cast<const float4*>(s);
        float4 v1 = *reinterpret_cast<const float4*>(s + 4);
        float4 v2 = *reinterpret_cast<const float4*>(s + 8);
        float4 v3 = *reinterpret_cast<const float4*>(s + 12);
        unsigned short* lr_ = &lds[r * 66 + c0];
        lr_[0]  = f2bf(v0.x); lr_[1]  = f2bf(v0.y); lr_[2]  = f2bf(v0.z); lr_[3]  = f2bf(v0.w);
        lr_[4]  = f2bf(v1.x); lr_[5]  = f2bf(v1.y); lr_[6]  = f2bf(v1.z); lr_[7]  = f2bf(v1.w);
        lr_[8]  = f2bf(v2.x); lr_[9]  = f2bf(v2.y); lr_[10] = f2bf(v2.z); lr_[11] = f2bf(v2.w);
        lr_[12] = f2bf(v3.x); lr_[13] = f2bf(v3.y); lr_[14] = f2bf(v3.z); lr_[15] = f2bf(v3.w);
    }
    __syncthreads();
    {
        int c = tid >> 2, q0 = (tid & 3) << 4;
        u16x8 o0, o1;
#pragma unroll
        for (int j = 0; j < 8; ++j) o0[j] = lds[(q0 + j) * 66 + c];
#pragma unroll
        for (int j = 0; j < 8; ++j) o1[j] = lds[(q0 + 8 + j) * 66 + c];
        unsigned short* d = d0 + (size_t)(tc * 64 + c) * R + tr * 64 + q0;
        *reinterpret_cast<u16x8*>(d) = o0;
        *reinterpret_cast<u16x8*>(d + 8) = o1;
    }
}

// ---------------------------------------------------------------------------
// 5) Fused gate+up GEMM (m97 structure): 128x128 tile, BK=64, 4 waves,
//    global_load_lds width-16 staging, linear LDS, 2-barrier loop.
//    XCD-aware grouping: mt innermost so B-panel sharers co-reside per XCD.
// ---------------------------------------------------------------------------
__global__ __launch_bounds__(256, 2) void gateup_kernel(
    const unsigned short* __restrict__ Xg,
    const unsigned short* __restrict__ Wgt,  // [e][i][h] bf16
    const unsigned short* __restrict__ Wut,
    const int* __restrict__ offs, unsigned short* __restrict__ hbuf)
{
    __shared__ unsigned short As[128 * 64];
    __shared__ unsigned short Bgs[128 * 64];
    __shared__ unsigned short Bus[128 * 64];

    int bid = blockIdx.x;                         // 0 .. 11263
    int slot = bid >> 3, xcd = bid & 7;
    int L = xcd * (NEXP * GU_NY * MT / 8) + slot; // contiguous logical chunk per XCD
    int mt = L & (MT - 1);
    int t = L >> 6;
    int ny = t % GU_NY;
    int e  = t / GU_NY;

    const int r0 = offs[e], r1 = offs[e + 1];
    const int m0 = r0 + mt * 128;
    if (m0 >= r1) return;
    const int n0 = ny * 128;

    const unsigned short* wg = Wgt + (size_t)e * IDIM * HDIM;
    const unsigned short* wu = Wut + (size_t)e * IDIM * HDIM;

    const int tid = threadIdx.x;
    const int lane = tid & 63, wv = tid >> 6;
    const int wr = (wv >> 1) * 64, wc = (wv & 1) * 64;
    const int lr = lane & 15, kg = (lane >> 4) * 8;
    const int srow = lane >> 3;            // 0..7
    const int scol = (lane & 7) * 8;       // 0..56

    f32x4 zero = {0.f, 0.f, 0.f, 0.f};
    f32x4 accg[4][4], accu[4][4];
#pragma unroll
    for (int m = 0; m < 4; ++m)
#pragma unroll
        for (int n = 0; n < 4; ++n) { accg[m][n] = zero; accu[m][n] = zero; }

    for (int k0 = 0; k0 < HDIM; k0 += 64) {
        __syncthreads();
#pragma unroll
        for (int i = 0; i < 4; ++i) {
            int chunk = i * 4 + wv;            // 0..15
            int row = chunk * 8 + srow;        // 0..127
            unsigned short* la = &As[chunk * 512 + lane * 8];
            unsigned short* lg = &Bgs[chunk * 512 + lane * 8];
            unsigned short* lu = &Bus[chunk * 512 + lane * 8];
            gload16(&Xg[(size_t)(m0 + row) * HDIM + k0 + scol], la);
            gload16(&wg[(size_t)(n0 + row) * HDIM + k0 + scol], lg);
            gload16(&wu[(size_t)(n0 + row) * HDIM + k0 + scol], lu);
        }
        __syncthreads();   // compiler drains vmcnt(0) before barrier

#pragma unroll
        for (int ks = 0; ks < 2; ++ks) {
            bf16x8 af[4], bg[4], bu[4];
#pragma unroll
            for (int m = 0; m < 4; ++m)
                af[m] = *reinterpret_cast<const bf16x8*>(&As[(wr + m * 16 + lr) * 64 + ks * 32 + kg]);
#pragma unroll
            for (int n = 0; n < 4; ++n) {
                bg[n] = *reinterpret_cast<const bf16x8*>(&Bgs[(wc + n * 16 + lr) * 64 + ks * 32 + kg]);
                bu[n] = *reinterpret_cast<const bf16x8*>(&Bus[(wc + n * 16 + lr) * 64 + ks * 32 + kg]);
            }
#pragma unroll
            for (int m = 0; m < 4; ++m)
#pragma unroll
                for (int n = 0; n < 4; ++n) {
                    accg[m][n] = __builtin_amdgcn_mfma_f32_16x16x32_bf16(af[m], bg[n], accg[m][n], 0, 0, 0);
                    accu[m][n] = __builtin_amdgcn_mfma_f32_16x16x32_bf16(af[m], bu[n], accu[m][n], 0, 0, 0);
                }
        }
    }

    const int rr = (lane >> 4) * 4;
#pragma unroll
    for (int m = 0; m < 4; ++m) {
#pragma unroll
        for (int r = 0; r < 4; ++r) {
            int grow = m0 + wr + m * 16 + rr + r;
            if (grow < r1) {
                unsigned short* hr = &hbuf[(size_t)grow * IDIM + n0 + wc + lr];
#pragma unroll
                for (int n = 0; n < 4; ++n) {
                    float g = accg[m][n][r];
                    float u = accu[m][n][r];
                    float s = g / (1.0f + __expf(-g));
                    hr[n * 16] = f2bf(s * u);
                }
            }
        }
    }
}

// ---------------------------------------------------------------------------
// 6) Down GEMM: same structure, K=IDIM, B = Wdt[e][h][i] bf16.
// ---------------------------------------------------------------------------
__global__ __launch_bounds__(256, 2) void down_kernel(
    const unsigned short* __restrict__ hbuf,
    const unsigned short* __restrict__ Wdt,   // [e][h][i] bf16
    const int* __restrict__ offs,
    const float* __restrict__ row_w,
    unsigned short* __restrict__ eo)
{
    __shared__ unsigned short As[128 * 64];
    __shared__ unsigned short Bs[128 * 64];

    int bid = blockIdx.x;                          // 0 .. 4095
    int slot = bid >> 3, xcd = bid & 7;
    int L = xcd * (NEXP * DN_NY * MT / 8) + slot;  // 512 per XCD
    int mt = L & (MT - 1);
    int t = L >> 6;
    int ny = t & (DN_NY - 1);
    int e  = t >> 3;

    const int r0 = offs[e], r1 = offs[e + 1];
    const int m0 = r0 + mt * 128;
    if (m0 >= r1) return;
    const int n0 = ny * 128;

    const unsigned short* wd = Wdt + (size_t)e * HDIM * IDIM;

    const int tid = threadIdx.x;
    const int lane = tid & 63, wv = tid >> 6;
    const int wr = (wv >> 1) * 64, wc = (wv & 1) * 64;
    const int lr = lane & 15, kg = (lane >> 4) * 8;
    const int srow = lane >> 3;
    const int scol = (lane & 7) * 8;

    f32x4 zero = {0.f, 0.f, 0.f, 0.f};
    f32x4 acc[4][4];
#pragma unroll
    for (int m = 0; m < 4; ++m)
#pragma unroll
        for (int n = 0; n < 4; ++n) acc[m][n] = zero;

    for (int k0 = 0; k0 < IDIM; k0 += 64) {
        __syncthreads();
#pragma unroll
        for (int i = 0; i < 4; ++i) {
            int chunk = i * 4 + wv;
            int row = chunk * 8 + srow;
            unsigned short* la = &As[chunk * 512 + lane * 8];
            unsigned short* lb = &Bs[chunk * 512 + lane * 8];
            gload16(&hbuf[(size_t)(m0 + row) * IDIM + k0 + scol], la);
            gload16(&wd[(size_t)(n0 + row) * IDIM + k0 + scol], lb);
        }
        __syncthreads();

#pragma unroll
        for (int ks = 0; ks < 2; ++ks) {
            bf16x8 af[4], bf[4];
#pragma unroll
            for (int m = 0; m < 4; ++m)
                af[m] = *reinterpret_cast<const bf16x8*>(&As[(wr + m * 16 + lr) * 64 + ks * 32 + kg]);
#pragma unroll
            for (int n = 0; n < 4; ++n)
                bf[n] = *reinterpret_cast<const bf16x8*>(&Bs[(wc + n * 16 + lr) * 64 + ks * 32 + kg]);
#pragma unroll
            for (int m = 0; m < 4; ++m)
#pragma unroll
                for (int n = 0; n < 4; ++n)
                    acc[m][n] = __builtin_amdgcn_mfma_f32_16x16x32_bf16(af[m], bf[n], acc[m][n], 0, 0, 0);
        }
    }

    const int rr = (lane >> 4) * 4;
#pragma unroll
    for (int m = 0; m < 4; ++m) {
#pragma unroll
        for (int r = 0; r < 4; ++r) {
            int grow = m0 + wr + m * 16 + rr + r;
            if (grow < r1) {
                float w = row_w[grow];
                unsigned short* er = &eo[(size_t)grow * HDIM + n0 + wc + lr];
#pragma unroll
                for (int n = 0; n < 4; ++n)
                    er[n * 16] = f2bf(acc[m][n][r] * w);
            }
        }
    }
}

// ---------------------------------------------------------------------------
// 7) Combine
// ---------------------------------------------------------------------------
__global__ __launch_bounds__(256) void combine_kernel(
    const unsigned short* __restrict__ eo, const int* __restrict__ pos_of,
    float* __restrict__ out)
{
    int t = blockIdx.x * 256 + threadIdx.x;
    int n = t >> 7;
    int c = (t & 127) << 3;
    int p0 = pos_of[n * 2 + 0];
    int p1 = pos_of[n * 2 + 1];
    uint4 a = *reinterpret_cast<const uint4*>(&eo[(size_t)p0 * HDIM + c]);
    uint4 b = *reinterpret_cast<const uint4*>(&eo[(size_t)p1 * HDIM + c]);
    float4 o0, o1;
    o0.x = bf2f(a.x & 0xffffu) + bf2f(b.x & 0xffffu);
    o0.y = bf2f(a.x >> 16)     + bf2f(b.x >> 16);
    o0.z = bf2f(a.y & 0xffffu) + bf2f(b.y & 0xffffu);
    o0.w = bf2f(a.y >> 16)     + bf2f(b.y >> 16);
    o1.x = bf2f(a.z & 0xffffu) + bf2f(b.z & 0xffffu);
    o1.y = bf2f(a.z >> 16)     + bf2f(b.z >> 16);
    o1.z = bf2f(a.w & 0xffffu) + bf2f(b.w & 0xffffu);
    o1.w = bf2f(a.w >> 16)     + bf2f(b.w >> 16);
    float* op = out + (size_t)n * HDIM + c;
    *reinterpret_cast<float4*>(op) = o0;
    *reinterpret_cast<float4*>(op + 4) = o1;
}

// ---------------------------------------------------------------------------
// ws layout (bytes):
//   [0,          17,039,360)   Xg bf16 [RPAD][HDIM]  (later aliased by eo)
//   [17,039,360, 63,897,600)   hbuf bf16 [RPAD][IDIM]
//   [63,897,600, 110,034,944)  Wgt bf16 [E][I][H]    (later aliased by Wdt)
//   [110,034,944,156,172,288)  Wut bf16 [E][I][H]
//   [156,172,288, ...)         meta
// peak ~150 MB
// ---------------------------------------------------------------------------
extern "C" void kernel_launch(void* const* d_in, const int* in_sizes, int n_in,
                              void* d_out, int out_size, void* d_ws, size_t ws_size,
                              hipStream_t stream)
{
    const float* x     = (const float*)d_in[0];
    const float* Wgate = (const float*)d_in[1];
    const float* bgate = (const float*)d_in[2];
    const float* Wg    = (const float*)d_in[3];
    const float* Wu    = (const float*)d_in[4];
    const float* Wd    = (const float*)d_in[5];
    float* out = (float*)d_out;
    float* logits = out + (size_t)NTOK * HDIM;

    char* ws = (char*)d_ws;
    unsigned short* Xg   = (unsigned short*)ws;                  // also eo
    unsigned short* hbuf = (unsigned short*)(ws + 17039360);
    unsigned short* Wgt  = (unsigned short*)(ws + 63897600);     // also Wdt
    unsigned short* Wut  = (unsigned short*)(ws + 110034944);
    char* meta = ws + 156172288;
    int*   counts = (int*)(meta);
    int*   offs   = (int*)(meta + 64);
    int*   cursor = (int*)(meta + 128);
    int*   topi   = (int*)(meta + 256);
    float* topv   = (float*)(meta + 33024);
    int*   pos_of = (int*)(meta + 65792);
    float* row_w  = (float*)(meta + 98560);

    hipMemsetAsync(counts, 0, 32, stream);
    gating_kernel<<<NTOK / 4, 256, 0, stream>>>(x, Wgate, bgate, logits, counts, topi, topv);
    offsets_kernel<<<1, 64, 0, stream>>>(counts, offs, cursor);
    scatter_kernel<<<NROWS / 4, 256, 0, stream>>>(x, topi, topv, cursor, row_w, pos_of, Xg);

    // weight convert+transpose: Wg,Wu [H][I] fp32 -> [I][H] bf16
    transpose_cvt_kernel<<<dim3(704, NEXP), 256, 0, stream>>>(Wg, Wgt, HDIM, IDIM, IDIM / 64);
    transpose_cvt_kernel<<<dim3(704, NEXP), 256, 0, stream>>>(Wu, Wut, HDIM, IDIM, IDIM / 64);

    gateup_kernel<<<NEXP * GU_NY * MT, 256, 0, stream>>>(Xg, Wgt, Wut, offs, hbuf);

    // Wd [I][H] fp32 -> [H][I] bf16, aliased over Wgt (dead after gateup)
    transpose_cvt_kernel<<<dim3(704, NEXP), 256, 0, stream>>>(Wd, Wgt, IDIM, HDIM, HDIM / 64);

    down_kernel<<<NEXP * DN_NY * MT, 256, 0, stream>>>(hbuf, Wgt, offs, row_w, Xg /*eo*/);
    combine_kernel<<<NTOK * HDIM / 8 / 256, 256, 0, stream>>>(Xg, pos_of, out);
}

// Round 3
// 515.240 us; speedup vs baseline: 6.4314x; 1.0883x over previous
//
#include <hip/hip_runtime.h>

// Problem constants
#define HDIM 1024
#define IDIM 2816
#define NEXP 8
#define NTOK 4096      // B*S
#define NROWS 8192     // NTOK * K(=2)
#define RPAD 8320      // NROWS + 128 pad rows (tile overrun)
#define MAXT 71        // max total 128-row tiles: floor(8192/128)+7
#define GU_NYT 44      // 2*IDIM/128
#define DN_NYT 8       // HDIM/128
#define GU_NWG (MAXT * GU_NYT)   // 3124
#define DN_NWG (MAXT * DN_NYT)   // 568

typedef short bf16x8 __attribute__((ext_vector_type(8)));
typedef float f32x4 __attribute__((ext_vector_type(4)));
typedef unsigned short u16x8 __attribute__((ext_vector_type(8)));

static __device__ __forceinline__ unsigned short f2bf(float f) {
    union { float f; unsigned int i; } v; v.f = f;
    return (unsigned short)((v.i + 0x7fffu + ((v.i >> 16) & 1u)) >> 16);  // RNE
}

// async global->LDS, 16B/lane; LDS dest = wave-uniform base + lane*16
static __device__ __forceinline__ void gload16(const void* g, void* l) {
    __builtin_amdgcn_global_load_lds(
        (const __attribute__((address_space(1))) unsigned int*)g,
        (__attribute__((address_space(3))) unsigned int*)l, 16, 0, 0);
}

// ---------------------------------------------------------------------------
// 1) Gating: one wave per token, fp64 accumulate for stable top-2 ordering.
// ---------------------------------------------------------------------------
__global__ __launch_bounds__(256) void gating_kernel(
    const float* __restrict__ x, const float* __restrict__ Wgate,
    const float* __restrict__ bgate, float* __restrict__ logits_out,
    int* __restrict__ counts, int* __restrict__ topi, float* __restrict__ topv)
{
    int wave = (blockIdx.x << 2) + (threadIdx.x >> 6);
    int lane = threadIdx.x & 63;
    if (wave >= NTOK) return;
    const float* xr = x + (size_t)wave * HDIM;

    double acc[NEXP];
#pragma unroll
    for (int e = 0; e < NEXP; ++e) acc[e] = 0.0;

    for (int it = 0; it < HDIM / 64; ++it) {
        int h = lane + (it << 6);
        float xv = xr[h];
        const float* wr = Wgate + (size_t)h * NEXP;
#pragma unroll
        for (int e = 0; e < NEXP; ++e) acc[e] += (double)xv * (double)wr[e];
    }
#pragma unroll
    for (int e = 0; e < NEXP; ++e) {
        double v = acc[e];
        for (int off = 32; off; off >>= 1) v += __shfl_xor(v, off, 64);
        acc[e] = v + (double)bgate[e];
    }
    float lf[NEXP];
#pragma unroll
    for (int e = 0; e < NEXP; ++e) lf[e] = (float)acc[e];

    if (lane < NEXP) logits_out[(size_t)wave * NEXP + lane] = lf[lane];

    if (lane == 0) {
        int i1 = 0; float v1 = lf[0];
#pragma unroll
        for (int e = 1; e < NEXP; ++e) if (lf[e] > v1) { v1 = lf[e]; i1 = e; }
        int i2 = -1; float v2 = -3.0e38f;
#pragma unroll
        for (int e = 0; e < NEXP; ++e) {
            if (e == i1) continue;
            if (lf[e] > v2) { v2 = lf[e]; i2 = e; }
        }
        topi[wave * 2 + 0] = i1; topv[wave * 2 + 0] = v1;
        topi[wave * 2 + 1] = i2; topv[wave * 2 + 1] = v2;
        atomicAdd(&counts[i1], 1);
        atomicAdd(&counts[i2], 1);
    }
}

// ---------------------------------------------------------------------------
// 2) Offsets + device-built tile table (e, m0) per 128-row tile
// ---------------------------------------------------------------------------
__global__ void offsets_kernel(const int* __restrict__ counts,
                               int* __restrict__ offs, int* __restrict__ cursor,
                               int* __restrict__ ntile, int* __restrict__ te,
                               int* __restrict__ tm0)
{
    if (threadIdx.x == 0 && blockIdx.x == 0) {
        int s = 0;
        for (int e = 0; e < NEXP; ++e) { offs[e] = s; cursor[e] = s; s += counts[e]; }
        offs[NEXP] = s;
        int nt = 0;
        for (int e = 0; e < NEXP; ++e) {
            int c = counts[e], base = offs[e];
            for (int mt = 0; mt * 128 < c; ++mt) { te[nt] = e; tm0[nt] = base + mt * 128; ++nt; }
        }
        *ntile = nt;
    }
}

// ---------------------------------------------------------------------------
// 3) Scatter: pack selected token rows as bf16 into Xg[pos]; record weight+token
// ---------------------------------------------------------------------------
__global__ __launch_bounds__(256) void scatter_kernel(
    const float* __restrict__ x, const int* __restrict__ topi,
    const float* __restrict__ topv, int* __restrict__ cursor,
    float* __restrict__ row_w, int* __restrict__ tok_of,
    unsigned short* __restrict__ Xg)
{
    int p = (blockIdx.x << 2) + (threadIdx.x >> 6);
    int lane = threadIdx.x & 63;
    if (p >= NROWS) return;
    int n = p >> 1;
    int e = topi[p];
    float w = topv[p];
    int pos = 0;
    if (lane == 0) {
        pos = atomicAdd(&cursor[e], 1);
        row_w[pos] = w;
        tok_of[pos] = n;
    }
    pos = __shfl(pos, 0, 64);
    const float* xr = x + (size_t)n * HDIM;
    unsigned short* dst = Xg + (size_t)pos * HDIM;
#pragma unroll
    for (int it = 0; it < HDIM / 256; ++it) {
        int idx = (it * 64 + lane) * 4;
        float4 v = *reinterpret_cast<const float4*>(&xr[idx]);
        ushort4 o;
        o.x = f2bf(v.x); o.y = f2bf(v.y); o.z = f2bf(v.z); o.w = f2bf(v.w);
        *reinterpret_cast<ushort4*>(&dst[idx]) = o;
    }
}

// ---------------------------------------------------------------------------
// 4a) Gate+Up convert+transpose into interleaved W2[e][2I][H]:
//     row r2 = ((i>>4)<<5) + (kind<<4) + (i&15); kind 0=gate 1=up.
//     64x64 tiles via LDS (pad 66).
// ---------------------------------------------------------------------------
__global__ __launch_bounds__(256) void transpose_cvt_gu_kernel(
    const float* __restrict__ Wg, const float* __restrict__ Wu,
    unsigned short* __restrict__ W2)
{
    __shared__ unsigned short lds[64 * 66];
    const int kind = blockIdx.z;
    const int e = blockIdx.y;
    const float* s0 = (kind ? Wu : Wg) + (size_t)e * HDIM * IDIM;
    unsigned short* d0 = W2 + (size_t)e * 2 * IDIM * HDIM;
    const int TC = IDIM / 64;
    int tt = blockIdx.x;
    int tr = tt / TC, tc = tt % TC;
    int tid = threadIdx.x;
    {
        int r = tid >> 2, c0 = (tid & 3) << 4;
        const float* s = s0 + (size_t)(tr * 64 + r) * IDIM + tc * 64 + c0;
        float4 v0 = *reinterpret_cast<const float4*>(s);
        float4 v1 = *reinterpret_cast<const float4*>(s + 4);
        float4 v2 = *reinterpret_cast<const float4*>(s + 8);
        float4 v3 = *reinterpret_cast<const float4*>(s + 12);
        unsigned short* lr_ = &lds[r * 66 + c0];
        lr_[0]  = f2bf(v0.x); lr_[1]  = f2bf(v0.y); lr_[2]  = f2bf(v0.z); lr_[3]  = f2bf(v0.w);
        lr_[4]  = f2bf(v1.x); lr_[5]  = f2bf(v1.y); lr_[6]  = f2bf(v1.z); lr_[7]  = f2bf(v1.w);
        lr_[8]  = f2bf(v2.x); lr_[9]  = f2bf(v2.y); lr_[10] = f2bf(v2.z); lr_[11] = f2bf(v2.w);
        lr_[12] = f2bf(v3.x); lr_[13] = f2bf(v3.y); lr_[14] = f2bf(v3.z); lr_[15] = f2bf(v3.w);
    }
    __syncthreads();
    {
        int c = tid >> 2, q0 = (tid & 3) << 4;
        u16x8 o0, o1;
#pragma unroll
        for (int j = 0; j < 8; ++j) o0[j] = lds[(q0 + j) * 66 + c];
#pragma unroll
        for (int j = 0; j < 8; ++j) o1[j] = lds[(q0 + 8 + j) * 66 + c];
        int i = tc * 64 + c;                                  // src column
        int r2 = ((i >> 4) << 5) + (kind << 4) + (i & 15);    // interleaved row
        unsigned short* d = d0 + (size_t)r2 * HDIM + tr * 64 + q0;
        *reinterpret_cast<u16x8*>(d) = o0;
        *reinterpret_cast<u16x8*>(d + 8) = o1;
    }
}

// 4b) Plain transpose for Wd: fp32 [I][H] -> bf16 [H][I]
__global__ __launch_bounds__(256) void transpose_cvt_d_kernel(
    const float* __restrict__ Wd, unsigned short* __restrict__ Wdt)
{
    __shared__ unsigned short lds[64 * 66];
    const int e = blockIdx.y;
    const float* s0 = Wd + (size_t)e * IDIM * HDIM;
    unsigned short* d0 = Wdt + (size_t)e * HDIM * IDIM;
    const int TC = HDIM / 64;
    int tt = blockIdx.x;
    int tr = tt / TC, tc = tt % TC;
    int tid = threadIdx.x;
    {
        int r = tid >> 2, c0 = (tid & 3) << 4;
        const float* s = s0 + (size_t)(tr * 64 + r) * HDIM + tc * 64 + c0;
        float4 v0 = *reinterpret_cast<const float4*>(s);
        float4 v1 = *reinterpret_cast<const float4*>(s + 4);
        float4 v2 = *reinterpret_cast<const float4*>(s + 8);
        float4 v3 = *reinterpret_cast<const float4*>(s + 12);
        unsigned short* lr_ = &lds[r * 66 + c0];
        lr_[0]  = f2bf(v0.x); lr_[1]  = f2bf(v0.y); lr_[2]  = f2bf(v0.z); lr_[3]  = f2bf(v0.w);
        lr_[4]  = f2bf(v1.x); lr_[5]  = f2bf(v1.y); lr_[6]  = f2bf(v1.z); lr_[7]  = f2bf(v1.w);
        lr_[8]  = f2bf(v2.x); lr_[9]  = f2bf(v2.y); lr_[10] = f2bf(v2.z); lr_[11] = f2bf(v2.w);
        lr_[12] = f2bf(v3.x); lr_[13] = f2bf(v3.y); lr_[14] = f2bf(v3.z); lr_[15] = f2bf(v3.w);
    }
    __syncthreads();
    {
        int c = tid >> 2, q0 = (tid & 3) << 4;
        u16x8 o0, o1;
#pragma unroll
        for (int j = 0; j < 8; ++j) o0[j] = lds[(q0 + j) * 66 + c];
#pragma unroll
        for (int j = 0; j < 8; ++j) o1[j] = lds[(q0 + 8 + j) * 66 + c];
        unsigned short* d = d0 + (size_t)(tc * 64 + c) * IDIM + tr * 64 + q0;
        *reinterpret_cast<u16x8*>(d) = o0;
        *reinterpret_cast<u16x8*>(d + 8) = o1;
    }
}

// ---------------------------------------------------------------------------
// 5) Fused gate+up GEMM over W2 (N = 2*IDIM, interleaved 16g/16u):
//    128x128 tile, BK=64, 4 waves, 2 LDS buffers (32KB), global_load_lds,
//    tile-table grid + bijective XCD chunking (ny-major for B-panel L2 reuse).
//    Epilogue: frag parity n&1 -> (gate, up) in the SAME lane -> silu fuse.
// ---------------------------------------------------------------------------
__global__ __launch_bounds__(256, 4) void gateup_kernel(
    const unsigned short* __restrict__ Xg,
    const unsigned short* __restrict__ W2,
    const int* __restrict__ offs,
    const int* __restrict__ ntile, const int* __restrict__ te,
    const int* __restrict__ tm0, unsigned short* __restrict__ hbuf)
{
    __shared__ unsigned short As[128 * 64];
    __shared__ unsigned short Bs[128 * 64];

    // bijective XCD chunking: nwg=3124 = 8*390+4
    int bid = blockIdx.x;
    int xcd = bid & 7, rest = bid >> 3;
    const int q = GU_NWG / 8, r = GU_NWG % 8;
    int wg = (xcd < r ? xcd * (q + 1) : r * (q + 1) + (xcd - r) * q) + rest;
    int t = wg % MAXT;           // tile (A panel) fast -> B panel reused in L2
    int ny = wg / MAXT;          // i2-tile

    if (t >= *ntile) return;
    const int e = te[t];
    const int m0 = tm0[t];
    const int r1 = offs[e + 1];
    const int n0 = ny * 128;     // i2 base

    const unsigned short* wb = W2 + (size_t)e * 2 * IDIM * HDIM;

    const int tid = threadIdx.x;
    const int lane = tid & 63, wv = tid >> 6;
    const int wr = (wv >> 1) * 64, wc = (wv & 1) * 64;
    const int lr = lane & 15, kg = (lane >> 4) * 8;
    const int srow = lane >> 3;            // 0..7
    const int scol = (lane & 7) * 8;       // 0..56

    f32x4 zero = {0.f, 0.f, 0.f, 0.f};
    f32x4 acc[4][4];
#pragma unroll
    for (int m = 0; m < 4; ++m)
#pragma unroll
        for (int n = 0; n < 4; ++n) acc[m][n] = zero;

    for (int k0 = 0; k0 < HDIM; k0 += 64) {
        __syncthreads();
#pragma unroll
        for (int i = 0; i < 4; ++i) {
            int chunk = i * 4 + wv;            // 0..15
            int row = chunk * 8 + srow;        // 0..127
            gload16(&Xg[(size_t)(m0 + row) * HDIM + k0 + scol], &As[chunk * 512 + lane * 8]);
            gload16(&wb[(size_t)(n0 + row) * HDIM + k0 + scol], &Bs[chunk * 512 + lane * 8]);
        }
        __syncthreads();

#pragma unroll
        for (int ks = 0; ks < 2; ++ks) {
            bf16x8 af[4], bf[4];
#pragma unroll
            for (int m = 0; m < 4; ++m)
                af[m] = *reinterpret_cast<const bf16x8*>(&As[(wr + m * 16 + lr) * 64 + ks * 32 + kg]);
#pragma unroll
            for (int n = 0; n < 4; ++n)
                bf[n] = *reinterpret_cast<const bf16x8*>(&Bs[(wc + n * 16 + lr) * 64 + ks * 32 + kg]);
#pragma unroll
            for (int m = 0; m < 4; ++m)
#pragma unroll
                for (int n = 0; n < 4; ++n)
                    acc[m][n] = __builtin_amdgcn_mfma_f32_16x16x32_bf16(af[m], bf[n], acc[m][n], 0, 0, 0);
        }
    }

    // epilogue: n even = gate, n odd = up (same lane, same i)
    const int rr = (lane >> 4) * 4;
    const int iloc0 = ((wc >> 5) << 4) + lr;        // wc=0 -> lr, wc=64 -> 32+lr
    const int col0 = ny * 64 + iloc0;
#pragma unroll
    for (int m = 0; m < 4; ++m) {
#pragma unroll
        for (int j = 0; j < 4; ++j) {
            int grow = m0 + wr + m * 16 + rr + j;
            if (grow < r1) {
                unsigned short* hr = &hbuf[(size_t)grow * IDIM + col0];
                float g0 = acc[m][0][j], u0 = acc[m][1][j];
                float g1 = acc[m][2][j], u1 = acc[m][3][j];
                hr[0]  = f2bf(g0 / (1.0f + __expf(-g0)) * u0);
                hr[16] = f2bf(g1 / (1.0f + __expf(-g1)) * u1);
            }
        }
    }
}

// ---------------------------------------------------------------------------
// 6) Down GEMM + fused combine: atomicAdd weighted rows into fp32 out.
// ---------------------------------------------------------------------------
__global__ __launch_bounds__(256, 4) void down_kernel(
    const unsigned short* __restrict__ hbuf,
    const unsigned short* __restrict__ Wdt,   // [e][h][i] bf16
    const int* __restrict__ offs,
    const int* __restrict__ ntile, const int* __restrict__ te,
    const int* __restrict__ tm0,
    const float* __restrict__ row_w, const int* __restrict__ tok_of,
    float* __restrict__ out)
{
    __shared__ unsigned short As[128 * 64];
    __shared__ unsigned short Bs[128 * 64];

    // nwg = 568 = 8*71 exactly
    int bid = blockIdx.x;
    int xcd = bid & 7, rest = bid >> 3;
    int wg = xcd * (DN_NWG / 8) + rest;
    int t = wg % MAXT;
    int ny = wg / MAXT;

    if (t >= *ntile) return;
    const int e = te[t];
    const int m0 = tm0[t];
    const int r1 = offs[e + 1];
    const int n0 = ny * 128;

    const unsigned short* wd = Wdt + (size_t)e * HDIM * IDIM;

    const int tid = threadIdx.x;
    const int lane = tid & 63, wv = tid >> 6;
    const int wr = (wv >> 1) * 64, wc = (wv & 1) * 64;
    const int lr = lane & 15, kg = (lane >> 4) * 8;
    const int srow = lane >> 3;
    const int scol = (lane & 7) * 8;

    f32x4 zero = {0.f, 0.f, 0.f, 0.f};
    f32x4 acc[4][4];
#pragma unroll
    for (int m = 0; m < 4; ++m)
#pragma unroll
        for (int n = 0; n < 4; ++n) acc[m][n] = zero;

    for (int k0 = 0; k0 < IDIM; k0 += 64) {
        __syncthreads();
#pragma unroll
        for (int i = 0; i < 4; ++i) {
            int chunk = i * 4 + wv;
            int row = chunk * 8 + srow;
            gload16(&hbuf[(size_t)(m0 + row) * IDIM + k0 + scol], &As[chunk * 512 + lane * 8]);
            gload16(&wd[(size_t)(n0 + row) * IDIM + k0 + scol], &Bs[chunk * 512 + lane * 8]);
        }
        __syncthreads();

#pragma unroll
        for (int ks = 0; ks < 2; ++ks) {
            bf16x8 af[4], bf[4];
#pragma unroll
            for (int m = 0; m < 4; ++m)
                af[m] = *reinterpret_cast<const bf16x8*>(&As[(wr + m * 16 + lr) * 64 + ks * 32 + kg]);
#pragma unroll
            for (int n = 0; n < 4; ++n)
                bf[n] = *reinterpret_cast<const bf16x8*>(&Bs[(wc + n * 16 + lr) * 64 + ks * 32 + kg]);
#pragma unroll
            for (int m = 0; m < 4; ++m)
#pragma unroll
                for (int n = 0; n < 4; ++n)
                    acc[m][n] = __builtin_amdgcn_mfma_f32_16x16x32_bf16(af[m], bf[n], acc[m][n], 0, 0, 0);
        }
    }

    const int rr = (lane >> 4) * 4;
#pragma unroll
    for (int m = 0; m < 4; ++m) {
#pragma unroll
        for (int j = 0; j < 4; ++j) {
            int grow = m0 + wr + m * 16 + rr + j;
            if (grow < r1) {
                float w = row_w[grow];
                int tok = tok_of[grow];
                float* orow = out + (size_t)tok * HDIM + n0 + wc + lr;
#pragma unroll
                for (int n = 0; n < 4; ++n)
                    atomicAdd(&orow[n * 16], acc[m][n][j] * w);
            }
        }
    }
}

// ---------------------------------------------------------------------------
// ws layout (bytes):
//   [0,          17,039,360)   Xg bf16 [RPAD][HDIM]
//   [17,039,360, 63,897,600)   hbuf bf16 [RPAD][IDIM]
//   [63,897,600, 156,172,288)  W2 bf16 [E][2I][H]   (later aliased by Wdt [E][H][I])
//   [156,172,288, ...)         meta
// ---------------------------------------------------------------------------
extern "C" void kernel_launch(void* const* d_in, const int* in_sizes, int n_in,
                              void* d_out, int out_size, void* d_ws, size_t ws_size,
                              hipStream_t stream)
{
    const float* x     = (const float*)d_in[0];
    const float* Wgate = (const float*)d_in[1];
    const float* bgate = (const float*)d_in[2];
    const float* Wg    = (const float*)d_in[3];
    const float* Wu    = (const float*)d_in[4];
    const float* Wd    = (const float*)d_in[5];
    float* out = (float*)d_out;
    float* logits = out + (size_t)NTOK * HDIM;

    char* ws = (char*)d_ws;
    unsigned short* Xg   = (unsigned short*)ws;
    unsigned short* hbuf = (unsigned short*)(ws + 17039360);
    unsigned short* W2   = (unsigned short*)(ws + 63897600);   // also Wdt
    char* meta = ws + 156172288;
    int*   counts = (int*)(meta);
    int*   offs   = (int*)(meta + 64);
    int*   cursor = (int*)(meta + 128);
    int*   ntile  = (int*)(meta + 192);
    int*   te     = (int*)(meta + 256);     // 128 ints
    int*   tm0    = (int*)(meta + 768);     // 128 ints
    int*   topi   = (int*)(meta + 2048);    // NROWS ints
    float* topv   = (float*)(meta + 34816);
    float* row_w  = (float*)(meta + 67584);
    int*   tok_of = (int*)(meta + 100352);

    hipMemsetAsync(counts, 0, 32, stream);
    hipMemsetAsync(out, 0, (size_t)NTOK * HDIM * sizeof(float), stream);

    gating_kernel<<<NTOK / 4, 256, 0, stream>>>(x, Wgate, bgate, logits, counts, topi, topv);
    offsets_kernel<<<1, 64, 0, stream>>>(counts, offs, cursor, ntile, te, tm0);
    scatter_kernel<<<NROWS / 4, 256, 0, stream>>>(x, topi, topv, cursor, row_w, tok_of, Xg);

    // Wg,Wu fp32 [H][I] -> interleaved bf16 W2 [2I][H]
    transpose_cvt_gu_kernel<<<dim3((HDIM / 64) * (IDIM / 64), NEXP, 2), 256, 0, stream>>>(Wg, Wu, W2);

    gateup_kernel<<<GU_NWG, 256, 0, stream>>>(Xg, W2, offs, ntile, te, tm0, hbuf);

    // Wd fp32 [I][H] -> bf16 [H][I], aliased over W2 (dead after gateup)
    transpose_cvt_d_kernel<<<dim3((IDIM / 64) * (HDIM / 64), NEXP), 256, 0, stream>>>(Wd, W2);

    down_kernel<<<DN_NWG, 256, 0, stream>>>(hbuf, W2, offs, ntile, te, tm0, row_w, tok_of, out);
}